// Round 6
// baseline (121.948 us; speedup 1.0000x reference)
//
#include <hip/hip_runtime.h>

// MHA: B=4 T=1024 E=1024 H=16 D=64, causal, f32 in/out, bf16 internal compute.
// cast -> GEMM1 (QKV plain [B,H,T,D]) -> transpose_v -> flash attn (QBLK=128) -> GEMM2
// R6: (a) V scatter removed from GEMM1 epilogue (plain write + LDS-tiled transpose kernel)
//     (b) attn QBLK 64->128: 2 row-groups/wave, 2x MFMA per staged K/V byte.

#define T_SZ 1024
#define E_SZ 1024
#define H_SZ 16
#define D_SZ 64

typedef __attribute__((ext_vector_type(8))) short bf16x8;
typedef __attribute__((ext_vector_type(4))) short bf16x4;
typedef __attribute__((ext_vector_type(4))) float f32x4;

static __device__ __forceinline__ unsigned short f2b(float f) {
  unsigned int u = __builtin_bit_cast(unsigned int, f);
  u += 0x7fffu + ((u >> 16) & 1u);   // RNE
  return (unsigned short)(u >> 16);
}

static __device__ __forceinline__ unsigned int cvt_pk(float lo, float hi) {
  unsigned int r;
  asm("v_cvt_pk_bf16_f32 %0, %1, %2" : "=v"(r) : "v"(lo), "v"(hi));
  return r;
}

static __device__ __forceinline__ void load_lds16(const void* g, void* l) {
  __builtin_amdgcn_global_load_lds(
      (const __attribute__((address_space(1))) void*)g,
      (__attribute__((address_space(3))) void*)l, 16, 0, 0);
}

// ---------------- fused cast f32 -> bf16 ----------------
__global__ void cast_all(const float* __restrict__ x, const float* __restrict__ wq,
                         const float* __restrict__ wk, const float* __restrict__ wv,
                         const float* __restrict__ wp,
                         unsigned short* __restrict__ xb,
                         unsigned short* __restrict__ wqkvb,
                         unsigned short* __restrict__ wpb) {
  int b = blockIdx.x;
  const float4* src;
  ushort4* dst;
  int i;
  if (b < 4096) {
    src = (const float4*)x; dst = (ushort4*)xb; i = b * 256 + threadIdx.x;
  } else {
    int a = (b - 4096) >> 10;
    i = ((b - 4096) & 1023) * 256 + threadIdx.x;
    src = (const float4*)(a == 0 ? wq : a == 1 ? wk : a == 2 ? wv : wp);
    dst = (ushort4*)(a == 3 ? wpb : wqkvb + (size_t)a * 1048576);
  }
  float4 v = src[i];
  ushort4 o;
  o.x = f2b(v.x); o.y = f2b(v.y); o.z = f2b(v.z); o.w = f2b(v.w);
  dst[i] = o;
}

// ---------------- GEMM C[M,N] = A[M,K] * B[N,K]^T ----------------
// 128x128 tile, 4 waves, BK=32, double-buffered LDS with prefetch.
// EPI=0: scatter bf16 to Q/K/V all plain [B,H,T,D]. EPI=1: f32 + bias -> out.
template <int EPI>
__global__ void gemm_bt(const unsigned short* __restrict__ A,
                        const unsigned short* __restrict__ Bm,
                        int M, int N, int K,
                        float* __restrict__ outF, const float* __restrict__ bias,
                        unsigned short* __restrict__ Qb,
                        unsigned short* __restrict__ Kb,
                        unsigned short* __restrict__ Vb) {
  __shared__ __align__(16) char lds[32768];   // 2 x (As 8K | Bs 8K)
  const int tid = threadIdx.x;
  const int wid = tid >> 6;
  const int lane = tid & 63;
  const int llo = lane & 15, lhi = lane >> 4;
  const int row0 = blockIdx.x * 128, col0 = blockIdx.y * 128;
  const int wr = (wid >> 1) * 64, wc = (wid & 1) * 64;

  f32x4 acc[4][4];
#pragma unroll
  for (int m = 0; m < 4; ++m)
#pragma unroll
    for (int n = 0; n < 4; ++n) {
      f32x4 z = {0.f, 0.f, 0.f, 0.f};
      acc[m][n] = z;
    }

  auto stage = [&](int kt, char* base) {
#pragma unroll
    for (int c = 0; c < 2; ++c) {
      int off = c * 4096 + tid * 16;
      int r = off >> 6, cb = off & 63;
      load_lds16((const char*)A + ((size_t)(row0 + r) * K + kt) * 2 + cb,
                 base + c * 4096 + wid * 1024);
      load_lds16((const char*)Bm + ((size_t)(col0 + r) * K + kt) * 2 + cb,
                 base + 8192 + c * 4096 + wid * 1024);
    }
  };

  stage(0, lds);
  __syncthreads();
  int buf = 0;

  for (int kt = 0; kt < K; kt += 32) {
    char* cur = lds + buf * 16384;
    if (kt + 32 < K) stage(kt + 32, lds + (buf ^ 1) * 16384);

    bf16x8 af[4], bfr[4];
#pragma unroll
    for (int m = 0; m < 4; ++m)
      af[m] = *reinterpret_cast<const bf16x8*>(cur + (wr + m * 16 + llo) * 64 + lhi * 16);
#pragma unroll
    for (int n = 0; n < 4; ++n)
      bfr[n] = *reinterpret_cast<const bf16x8*>(cur + 8192 + (wc + n * 16 + llo) * 64 + lhi * 16);
#pragma unroll
    for (int m = 0; m < 4; ++m)
#pragma unroll
      for (int n = 0; n < 4; ++n)
        acc[m][n] = __builtin_amdgcn_mfma_f32_16x16x32_bf16(af[m], bfr[n], acc[m][n], 0, 0, 0);
    __syncthreads();
    buf ^= 1;
  }

#pragma unroll
  for (int m = 0; m < 4; ++m)
#pragma unroll
    for (int n = 0; n < 4; ++n)
#pragma unroll
      for (int r = 0; r < 4; ++r) {
        int grow = row0 + wr + m * 16 + lhi * 4 + r;
        int gcol = col0 + wc + n * 16 + llo;
        float v = acc[m][n][r];
        if (EPI == 0) {
          int b = grow >> 10, t = grow & 1023;
          int which = gcol >> 10, hd = gcol & 1023;
          int h = hd >> 6, d = hd & 63;
          unsigned short* dst = (which == 0) ? Qb : (which == 1) ? Kb : Vb;
          dst[(((size_t)(b * H_SZ + h)) * T_SZ + t) * D_SZ + d] = f2b(v);
        } else {
          outF[(size_t)grow * N + gcol] = v + bias[gcol];
        }
      }
}

// ---------------- V transpose: [B,H,T,D] -> [B,H,D,T], LDS-tiled ----------------
__global__ void transpose_v(const unsigned short* __restrict__ Vb,
                            unsigned short* __restrict__ Vtb) {
  __shared__ unsigned short tile[64 * 71 + 8];   // [64 d][71 t] (pad breaks banks)
  const int tid = threadIdx.x;
  const int bh = blockIdx.y;
  const int t0 = blockIdx.x * 64;
  const size_t base = (size_t)bh * (T_SZ * D_SZ);
#pragma unroll
  for (int u = 0; u < 2; ++u) {
    int cid = u * 256 + tid;
    int r = cid >> 3, ck = cid & 7;          // t-row, 8-wide d-chunk (coalesced 16B)
    bf16x8 v = *reinterpret_cast<const bf16x8*>(Vb + base + (size_t)(t0 + r) * D_SZ + ck * 8);
#pragma unroll
    for (int j = 0; j < 8; ++j)
      tile[(ck * 8 + j) * 71 + r] = (unsigned short)v[j];
  }
  __syncthreads();
#pragma unroll
  for (int u = 0; u < 2; ++u) {
    int cid = u * 256 + tid;
    int d = cid >> 3, tc = cid & 7;          // d-row, 8-wide t-chunk (coalesced 16B)
    bf16x8 o;
#pragma unroll
    for (int j = 0; j < 8; ++j)
      o[j] = (short)tile[d * 71 + tc * 8 + j];
    *reinterpret_cast<bf16x8*>(Vtb + base + (size_t)d * T_SZ + t0 + tc * 8) = o;
  }
}

// ---------------- flash attention, causal, S^T layout, QBLK=128 ----------------
// grid (8, 64) XCD-swizzled -> (blkx, bh); 256 thr = 4 waves; each wave owns 2
// groups of 16 q-rows (g=0: rows qb..qb+63 across waves, g=1: qb+64..qb+127).
// Groups processed sequentially per staged K/V tile (reuse sacc/p/Ps).
// Protocol frozen: stage -> barrier -> compute -> barrier (dbuf raced, R2/R3).
__global__ void attn_kernel(const unsigned short* __restrict__ Q,
                            const unsigned short* __restrict__ K,
                            const unsigned short* __restrict__ Vt,
                            unsigned short* __restrict__ O) {
  __shared__ __align__(16) char smem[24576];  // K 8K | V 8K | Ps 4x2K
  const int tid = threadIdx.x, wid = tid >> 6, lane = tid & 63;
  const int llo = lane & 15, lhi = lane >> 4;
  const int fid = blockIdx.y * 8 + blockIdx.x;
  const int wi = (fid & 7) * 64 + (fid >> 3);   // 8 bh per XCD -> K/V L2-resident
  const int blkx = wi & 7;
  const int bh = wi >> 3;
  const size_t bhbase = (size_t)bh * (T_SZ * D_SZ);
  char* Ks = smem;
  char* Vs = smem + 8192;
  char* Ps = smem + 16384 + wid * 2048;

  int qrow[2];
  bf16x8 bq[2][2];
#pragma unroll
  for (int g = 0; g < 2; ++g) {
    qrow[g] = blkx * 128 + g * 64 + wid * 16 + llo;
    const unsigned short* qp = Q + bhbase + (size_t)qrow[g] * D_SZ + lhi * 8;
    bq[g][0] = *reinterpret_cast<const bf16x8*>(qp);
    bq[g][1] = *reinterpret_cast<const bf16x8*>(qp + 32);
  }

  f32x4 oacc[2][4];
  float mrun[2], lrun[2];
#pragma unroll
  for (int g = 0; g < 2; ++g) {
    mrun[g] = -1e30f; lrun[g] = 0.f;
#pragma unroll
    for (int dc = 0; dc < 4; ++dc) {
      f32x4 z = {0.f, 0.f, 0.f, 0.f};
      oacc[g][dc] = z;
    }
  }
  const float scale = 0.125f;

  for (int it = 0; it <= 2 * blkx + 1; ++it) {
    const int kv = it * 64;
#pragma unroll
    for (int c = 0; c < 2; ++c) {
      int off = c * 4096 + tid * 16;
      int row = off >> 7, inb = off & 127;
      int sw = inb ^ ((row & 7) << 4);
      load_lds16((const char*)(K + bhbase + (size_t)(kv + row) * D_SZ) + sw,
                 Ks + c * 4096 + wid * 1024);
      load_lds16((const char*)(Vt + bhbase + (size_t)row * T_SZ + kv) + sw,
                 Vs + c * 4096 + wid * 1024);
    }
    __syncthreads();

#pragma unroll
    for (int g = 0; g < 2; ++g) {
      const int qtg = 2 * blkx + g;
      if (it > qtg) continue;   // uniform: g=0's fully-masked last tile skipped

      // S^T = K Q^T : A = K rows (keys), B = Q^T
      f32x4 sacc[4];
#pragma unroll
      for (int c = 0; c < 4; ++c) { f32x4 z = {0.f, 0.f, 0.f, 0.f}; sacc[c] = z; }
#pragma unroll
      for (int seg = 0; seg < 2; ++seg)
#pragma unroll
        for (int c = 0; c < 4; ++c) {
          int key = c * 16 + llo;
          bf16x8 ak = *reinterpret_cast<const bf16x8*>(
              Ks + key * 128 + ((seg * 64 + lhi * 16) ^ ((key & 7) << 4)));
          sacc[c] = __builtin_amdgcn_mfma_f32_16x16x32_bf16(ak, bq[g][seg], sacc[c], 0, 0, 0);
        }

      // softmax: lane holds 16 S^T values of its q-row (keys c*16 + lhi*4 + r)
      const bool diag = (it == qtg);
      float p[4][4];
      float pm = -1e30f;
#pragma unroll
      for (int c = 0; c < 4; ++c)
#pragma unroll
        for (int r = 0; r < 4; ++r) {
          float s = sacc[c][r] * scale;
          if (diag && (kv + c * 16 + lhi * 4 + r > qrow[g])) s = -1e30f;
          p[c][r] = s;
          pm = fmaxf(pm, s);
        }
      pm = fmaxf(pm, __shfl_xor(pm, 16, 64));
      pm = fmaxf(pm, __shfl_xor(pm, 32, 64));
      float mnew = fmaxf(mrun[g], pm);
      float alpha = __expf(mrun[g] - mnew);
      mrun[g] = mnew;

      float ps = 0.f;
#pragma unroll
      for (int c = 0; c < 4; ++c) {
#pragma unroll
        for (int r = 0; r < 4; ++r) {
          p[c][r] = __expf(p[c][r] - mnew);
          ps += p[c][r];
        }
        unsigned int w0 = cvt_pk(p[c][0], p[c][1]);
        unsigned int w1 = cvt_pk(p[c][2], p[c][3]);
        unsigned long long packed = ((unsigned long long)w1 << 32) | w0;
        *reinterpret_cast<bf16x4*>(
            Ps + llo * 128 + ((c * 32 + lhi * 8) ^ ((llo & 7) << 4))) =
            __builtin_bit_cast(bf16x4, packed);
      }
      // Hard fence: Ps ds_writes retired before PV ds_reads (rule-18 pattern).
      asm volatile("s_waitcnt lgkmcnt(0)" ::: "memory");
      __builtin_amdgcn_sched_barrier(0);

      ps += __shfl_xor(ps, 16, 64);
      ps += __shfl_xor(ps, 32, 64);
      lrun[g] = lrun[g] * alpha + ps;
#pragma unroll
      for (int dc = 0; dc < 4; ++dc)
#pragma unroll
        for (int r = 0; r < 4; ++r) oacc[g][dc][r] *= alpha;

      // O^T += V^T P^T : A = V^T rows (d), B = P^T (from per-wave LDS)
#pragma unroll
      for (int seg = 0; seg < 2; ++seg) {
        bf16x8 bp = *reinterpret_cast<const bf16x8*>(
            Ps + llo * 128 + ((seg * 64 + lhi * 16) ^ ((llo & 7) << 4)));
#pragma unroll
        for (int dc = 0; dc < 4; ++dc) {
          int d = dc * 16 + llo;
          bf16x8 av = *reinterpret_cast<const bf16x8*>(
              Vs + d * 128 + ((seg * 64 + lhi * 16) ^ ((d & 7) << 4)));
          oacc[g][dc] = __builtin_amdgcn_mfma_f32_16x16x32_bf16(av, bp, oacc[g][dc], 0, 0, 0);
        }
      }
    }
    __syncthreads();
  }

  // O^T -> O[b][t=q][h*64+d], d = dc*16 + lhi*4 + r
  const int b = bh >> 4, h = bh & 15;
#pragma unroll
  for (int g = 0; g < 2; ++g) {
    float inv = 1.f / lrun[g];
#pragma unroll
    for (int dc = 0; dc < 4; ++dc) {
      unsigned int w0 = cvt_pk(oacc[g][dc][0] * inv, oacc[g][dc][1] * inv);
      unsigned int w1 = cvt_pk(oacc[g][dc][2] * inv, oacc[g][dc][3] * inv);
      unsigned int* op = reinterpret_cast<unsigned int*>(
          O + ((size_t)b * T_SZ + qrow[g]) * E_SZ + h * D_SZ + dc * 16 + lhi * 4);
      op[0] = w0;
      op[1] = w1;
    }
  }
}

// ---------------- launch ----------------
extern "C" void kernel_launch(void* const* d_in, const int* in_sizes, int n_in,
                              void* d_out, int out_size, void* d_ws, size_t ws_size,
                              hipStream_t stream) {
  const float* x  = (const float*)d_in[0];
  const float* Wq = (const float*)d_in[1];
  const float* Wk = (const float*)d_in[2];
  const float* Wv = (const float*)d_in[3];
  const float* Wp = (const float*)d_in[4];
  const float* bp = (const float*)d_in[5];
  float* out = (float*)d_out;

  char* ws = (char*)d_ws;
  unsigned short* xb   = (unsigned short*)(ws);                    // 8 MB [4096,1024]
  unsigned short* wqkv = (unsigned short*)(ws + (8u << 20));       // 6 MB [3072,1024]
  unsigned short* wp   = (unsigned short*)(ws + (14u << 20));      // 2 MB [1024,1024]
  unsigned short* Qb   = (unsigned short*)(ws + (16u << 20));      // 8 MB [B,H,T,D]
  unsigned short* Kb   = (unsigned short*)(ws + (24u << 20));      // 8 MB [B,H,T,D]
  unsigned short* Vb   = (unsigned short*)(ws + (32u << 20));      // 8 MB [B,H,T,D]
  unsigned short* Ob   = (unsigned short*)(ws + (40u << 20));      // 8 MB [B,T,E]
  unsigned short* Vtb  = xb;   // aliases xb: dead after GEMM1, Vtb written after

  cast_all<<<8192, 256, 0, stream>>>(x, Wq, Wk, Wv, Wp, xb, wqkv, wp);

  gemm_bt<0><<<dim3(32, 24), 256, 0, stream>>>(xb, wqkv, 4096, 3072, 1024,
                                               nullptr, nullptr, Qb, Kb, Vb);
  transpose_v<<<dim3(16, 64), 256, 0, stream>>>(Vb, Vtb);
  attn_kernel<<<dim3(8, 64), 256, 0, stream>>>(Qb, Kb, Vtb, Ob);
  gemm_bt<1><<<dim3(32, 8), 256, 0, stream>>>(Ob, wp, 4096, 1024, 1024,
                                              out, bp, nullptr, nullptr, nullptr);
}

// Round 7
// 103.917 us; speedup vs baseline: 1.1735x; 1.1735x over previous
//
#include <hip/hip_runtime.h>

// MHA: B=4 T=1024 E=1024 H=16 D=64, causal, f32 in/out, bf16 internal compute.
// cast -> GEMM1 (QKV plain [B,H,T,D]) -> transpose_v -> flash attn (QBLK=128, 8 waves)
// -> GEMM2 (+bias)
// R7: attn = 512 thr / 8 waves, each wave 16 q-rows in parallel (R6's serial 2-group
//     regressed: doubled critical-path compute depth). Stage events stay halved vs R5.

#define T_SZ 1024
#define E_SZ 1024
#define H_SZ 16
#define D_SZ 64

typedef __attribute__((ext_vector_type(8))) short bf16x8;
typedef __attribute__((ext_vector_type(4))) short bf16x4;
typedef __attribute__((ext_vector_type(4))) float f32x4;

static __device__ __forceinline__ unsigned short f2b(float f) {
  unsigned int u = __builtin_bit_cast(unsigned int, f);
  u += 0x7fffu + ((u >> 16) & 1u);   // RNE
  return (unsigned short)(u >> 16);
}

static __device__ __forceinline__ unsigned int cvt_pk(float lo, float hi) {
  unsigned int r;
  asm("v_cvt_pk_bf16_f32 %0, %1, %2" : "=v"(r) : "v"(lo), "v"(hi));
  return r;
}

static __device__ __forceinline__ void load_lds16(const void* g, void* l) {
  __builtin_amdgcn_global_load_lds(
      (const __attribute__((address_space(1))) void*)g,
      (__attribute__((address_space(3))) void*)l, 16, 0, 0);
}

// ---------------- fused cast f32 -> bf16 ----------------
__global__ void cast_all(const float* __restrict__ x, const float* __restrict__ wq,
                         const float* __restrict__ wk, const float* __restrict__ wv,
                         const float* __restrict__ wp,
                         unsigned short* __restrict__ xb,
                         unsigned short* __restrict__ wqkvb,
                         unsigned short* __restrict__ wpb) {
  int b = blockIdx.x;
  const float4* src;
  ushort4* dst;
  int i;
  if (b < 4096) {
    src = (const float4*)x; dst = (ushort4*)xb; i = b * 256 + threadIdx.x;
  } else {
    int a = (b - 4096) >> 10;
    i = ((b - 4096) & 1023) * 256 + threadIdx.x;
    src = (const float4*)(a == 0 ? wq : a == 1 ? wk : a == 2 ? wv : wp);
    dst = (ushort4*)(a == 3 ? wpb : wqkvb + (size_t)a * 1048576);
  }
  float4 v = src[i];
  ushort4 o;
  o.x = f2b(v.x); o.y = f2b(v.y); o.z = f2b(v.z); o.w = f2b(v.w);
  dst[i] = o;
}

// ---------------- GEMM C[M,N] = A[M,K] * B[N,K]^T ----------------
// 128x128 tile, 4 waves, BK=32, double-buffered LDS with prefetch.
template <int EPI>
__global__ void gemm_bt(const unsigned short* __restrict__ A,
                        const unsigned short* __restrict__ Bm,
                        int M, int N, int K,
                        float* __restrict__ outF, const float* __restrict__ bias,
                        unsigned short* __restrict__ Qb,
                        unsigned short* __restrict__ Kb,
                        unsigned short* __restrict__ Vb) {
  __shared__ __align__(16) char lds[32768];   // 2 x (As 8K | Bs 8K)
  const int tid = threadIdx.x;
  const int wid = tid >> 6;
  const int lane = tid & 63;
  const int llo = lane & 15, lhi = lane >> 4;
  const int row0 = blockIdx.x * 128, col0 = blockIdx.y * 128;
  const int wr = (wid >> 1) * 64, wc = (wid & 1) * 64;

  f32x4 acc[4][4];
#pragma unroll
  for (int m = 0; m < 4; ++m)
#pragma unroll
    for (int n = 0; n < 4; ++n) {
      f32x4 z = {0.f, 0.f, 0.f, 0.f};
      acc[m][n] = z;
    }

  auto stage = [&](int kt, char* base) {
#pragma unroll
    for (int c = 0; c < 2; ++c) {
      int off = c * 4096 + tid * 16;
      int r = off >> 6, cb = off & 63;
      load_lds16((const char*)A + ((size_t)(row0 + r) * K + kt) * 2 + cb,
                 base + c * 4096 + wid * 1024);
      load_lds16((const char*)Bm + ((size_t)(col0 + r) * K + kt) * 2 + cb,
                 base + 8192 + c * 4096 + wid * 1024);
    }
  };

  stage(0, lds);
  __syncthreads();
  int buf = 0;

  for (int kt = 0; kt < K; kt += 32) {
    char* cur = lds + buf * 16384;
    if (kt + 32 < K) stage(kt + 32, lds + (buf ^ 1) * 16384);

    bf16x8 af[4], bfr[4];
#pragma unroll
    for (int m = 0; m < 4; ++m)
      af[m] = *reinterpret_cast<const bf16x8*>(cur + (wr + m * 16 + llo) * 64 + lhi * 16);
#pragma unroll
    for (int n = 0; n < 4; ++n)
      bfr[n] = *reinterpret_cast<const bf16x8*>(cur + 8192 + (wc + n * 16 + llo) * 64 + lhi * 16);
#pragma unroll
    for (int m = 0; m < 4; ++m)
#pragma unroll
      for (int n = 0; n < 4; ++n)
        acc[m][n] = __builtin_amdgcn_mfma_f32_16x16x32_bf16(af[m], bfr[n], acc[m][n], 0, 0, 0);
    __syncthreads();
    buf ^= 1;
  }

#pragma unroll
  for (int m = 0; m < 4; ++m)
#pragma unroll
    for (int n = 0; n < 4; ++n)
#pragma unroll
      for (int r = 0; r < 4; ++r) {
        int grow = row0 + wr + m * 16 + lhi * 4 + r;
        int gcol = col0 + wc + n * 16 + llo;
        float v = acc[m][n][r];
        if (EPI == 0) {
          int b = grow >> 10, t = grow & 1023;
          int which = gcol >> 10, hd = gcol & 1023;
          int h = hd >> 6, d = hd & 63;
          unsigned short* dst = (which == 0) ? Qb : (which == 1) ? Kb : Vb;
          dst[(((size_t)(b * H_SZ + h)) * T_SZ + t) * D_SZ + d] = f2b(v);
        } else {
          outF[(size_t)grow * N + gcol] = v + bias[gcol];
        }
      }
}

// ---------------- V transpose: [B,H,T,D] -> [B,H,D,T], LDS-tiled ----------------
__global__ void transpose_v(const unsigned short* __restrict__ Vb,
                            unsigned short* __restrict__ Vtb) {
  __shared__ unsigned short tile[64 * 71 + 8];
  const int tid = threadIdx.x;
  const int bh = blockIdx.y;
  const int t0 = blockIdx.x * 64;
  const size_t base = (size_t)bh * (T_SZ * D_SZ);
#pragma unroll
  for (int u = 0; u < 2; ++u) {
    int cid = u * 256 + tid;
    int r = cid >> 3, ck = cid & 7;
    bf16x8 v = *reinterpret_cast<const bf16x8*>(Vb + base + (size_t)(t0 + r) * D_SZ + ck * 8);
#pragma unroll
    for (int j = 0; j < 8; ++j)
      tile[(ck * 8 + j) * 71 + r] = (unsigned short)v[j];
  }
  __syncthreads();
#pragma unroll
  for (int u = 0; u < 2; ++u) {
    int cid = u * 256 + tid;
    int d = cid >> 3, tc = cid & 7;
    bf16x8 o;
#pragma unroll
    for (int j = 0; j < 8; ++j)
      o[j] = (short)tile[d * 71 + tc * 8 + j];
    *reinterpret_cast<bf16x8*>(Vtb + base + (size_t)d * T_SZ + t0 + tc * 8) = o;
  }
}

// ---------------- flash attention, causal, S^T layout, QBLK=128, 8 waves ----------------
// grid (8, 64) XCD-swizzled -> (blkx, bh); 512 thr = 8 waves x 16 q-rows, all parallel.
// Wave w owns rows blkx*128 + w*16 .. +16; its last active tile = 2*blkx + (w>>2).
// Protocol frozen: stage -> barrier -> compute -> barrier (dbuf raced, R2/R3).
__global__ void attn_kernel(const unsigned short* __restrict__ Q,
                            const unsigned short* __restrict__ K,
                            const unsigned short* __restrict__ Vt,
                            unsigned short* __restrict__ O) {
  __shared__ __align__(16) char smem[32768];  // K 8K | V 8K | Ps 8x2K
  const int tid = threadIdx.x, wid = tid >> 6, lane = tid & 63;
  const int llo = lane & 15, lhi = lane >> 4;
  const int fid = blockIdx.y * 8 + blockIdx.x;
  const int wi = (fid & 7) * 64 + (fid >> 3);   // 8 bh per XCD -> K/V L2-resident
  const int blkx = wi & 7;
  const int bh = wi >> 3;
  const size_t bhbase = (size_t)bh * (T_SZ * D_SZ);
  char* Ks = smem;
  char* Vs = smem + 8192;
  char* Ps = smem + 16384 + wid * 2048;

  const int qrow = blkx * 128 + wid * 16 + llo;
  const int myqt = 2 * blkx + (wid >> 2);   // wave's last active tile (uniform)
  bf16x8 bq[2];
  {
    const unsigned short* qp = Q + bhbase + (size_t)qrow * D_SZ + lhi * 8;
    bq[0] = *reinterpret_cast<const bf16x8*>(qp);
    bq[1] = *reinterpret_cast<const bf16x8*>(qp + 32);
  }

  f32x4 oacc[4];
#pragma unroll
  for (int dc = 0; dc < 4; ++dc) {
    f32x4 z = {0.f, 0.f, 0.f, 0.f};
    oacc[dc] = z;
  }
  float mrun = -1e30f, lrun = 0.f;
  const float scale = 0.125f;

  for (int it = 0; it <= 2 * blkx + 1; ++it) {
    const int kv = it * 64;
    // stage: 512 thr x 16B = 8KB per instr; one K + one V load per thread
    {
      int off = tid * 16;
      int row = off >> 7, inb = off & 127;
      int sw = inb ^ ((row & 7) << 4);
      load_lds16((const char*)(K + bhbase + (size_t)(kv + row) * D_SZ) + sw,
                 Ks + wid * 1024);
      load_lds16((const char*)(Vt + bhbase + (size_t)row * T_SZ + kv) + sw,
                 Vs + wid * 1024);
    }
    __syncthreads();

    if (it <= myqt) {   // wave-uniform causal skip
      // S^T = K Q^T : A = K rows (keys), B = Q^T
      f32x4 sacc[4];
#pragma unroll
      for (int c = 0; c < 4; ++c) { f32x4 z = {0.f, 0.f, 0.f, 0.f}; sacc[c] = z; }
#pragma unroll
      for (int seg = 0; seg < 2; ++seg)
#pragma unroll
        for (int c = 0; c < 4; ++c) {
          int key = c * 16 + llo;
          bf16x8 ak = *reinterpret_cast<const bf16x8*>(
              Ks + key * 128 + ((seg * 64 + lhi * 16) ^ ((key & 7) << 4)));
          sacc[c] = __builtin_amdgcn_mfma_f32_16x16x32_bf16(ak, bq[seg], sacc[c], 0, 0, 0);
        }

      // softmax: lane holds 16 S^T values of its q-row (keys c*16 + lhi*4 + r)
      const bool diag = (it == myqt);
      float p[4][4];
      float pm = -1e30f;
#pragma unroll
      for (int c = 0; c < 4; ++c)
#pragma unroll
        for (int r = 0; r < 4; ++r) {
          float s = sacc[c][r] * scale;
          if (diag && (kv + c * 16 + lhi * 4 + r > qrow)) s = -1e30f;
          p[c][r] = s;
          pm = fmaxf(pm, s);
        }
      pm = fmaxf(pm, __shfl_xor(pm, 16, 64));
      pm = fmaxf(pm, __shfl_xor(pm, 32, 64));
      float mnew = fmaxf(mrun, pm);
      float alpha = __expf(mrun - mnew);
      mrun = mnew;

      float ps = 0.f;
#pragma unroll
      for (int c = 0; c < 4; ++c) {
#pragma unroll
        for (int r = 0; r < 4; ++r) {
          p[c][r] = __expf(p[c][r] - mnew);
          ps += p[c][r];
        }
        unsigned int w0 = cvt_pk(p[c][0], p[c][1]);
        unsigned int w1 = cvt_pk(p[c][2], p[c][3]);
        unsigned long long packed = ((unsigned long long)w1 << 32) | w0;
        *reinterpret_cast<bf16x4*>(
            Ps + llo * 128 + ((c * 32 + lhi * 8) ^ ((llo & 7) << 4))) =
            __builtin_bit_cast(bf16x4, packed);
      }
      // Hard fence: Ps ds_writes retired before PV ds_reads (rule-18 pattern).
      asm volatile("s_waitcnt lgkmcnt(0)" ::: "memory");
      __builtin_amdgcn_sched_barrier(0);

      ps += __shfl_xor(ps, 16, 64);
      ps += __shfl_xor(ps, 32, 64);
      lrun = lrun * alpha + ps;
#pragma unroll
      for (int dc = 0; dc < 4; ++dc)
#pragma unroll
        for (int r = 0; r < 4; ++r) oacc[dc][r] *= alpha;

      // O^T += V^T P^T : A = V^T rows (d), B = P^T (from per-wave LDS)
#pragma unroll
      for (int seg = 0; seg < 2; ++seg) {
        bf16x8 bp = *reinterpret_cast<const bf16x8*>(
            Ps + llo * 128 + ((seg * 64 + lhi * 16) ^ ((llo & 7) << 4)));
#pragma unroll
        for (int dc = 0; dc < 4; ++dc) {
          int d = dc * 16 + llo;
          bf16x8 av = *reinterpret_cast<const bf16x8*>(
              Vs + d * 128 + ((seg * 64 + lhi * 16) ^ ((d & 7) << 4)));
          oacc[dc] = __builtin_amdgcn_mfma_f32_16x16x32_bf16(av, bp, oacc[dc], 0, 0, 0);
        }
      }
    }
    __syncthreads();
  }

  // O^T -> O[b][t=q][h*64+d], d = dc*16 + lhi*4 + r
  const int b = bh >> 4, h = bh & 15;
  float inv = 1.f / lrun;
#pragma unroll
  for (int dc = 0; dc < 4; ++dc) {
    unsigned int w0 = cvt_pk(oacc[dc][0] * inv, oacc[dc][1] * inv);
    unsigned int w1 = cvt_pk(oacc[dc][2] * inv, oacc[dc][3] * inv);
    unsigned int* op = reinterpret_cast<unsigned int*>(
        O + ((size_t)b * T_SZ + qrow) * E_SZ + h * D_SZ + dc * 16 + lhi * 4);
    op[0] = w0;
    op[1] = w1;
  }
}

// ---------------- launch ----------------
extern "C" void kernel_launch(void* const* d_in, const int* in_sizes, int n_in,
                              void* d_out, int out_size, void* d_ws, size_t ws_size,
                              hipStream_t stream) {
  const float* x  = (const float*)d_in[0];
  const float* Wq = (const float*)d_in[1];
  const float* Wk = (const float*)d_in[2];
  const float* Wv = (const float*)d_in[3];
  const float* Wp = (const float*)d_in[4];
  const float* bp = (const float*)d_in[5];
  float* out = (float*)d_out;

  char* ws = (char*)d_ws;
  unsigned short* xb   = (unsigned short*)(ws);                    // 8 MB [4096,1024]
  unsigned short* wqkv = (unsigned short*)(ws + (8u << 20));       // 6 MB [3072,1024]
  unsigned short* wp   = (unsigned short*)(ws + (14u << 20));      // 2 MB [1024,1024]
  unsigned short* Qb   = (unsigned short*)(ws + (16u << 20));      // 8 MB [B,H,T,D]
  unsigned short* Kb   = (unsigned short*)(ws + (24u << 20));      // 8 MB [B,H,T,D]
  unsigned short* Vb   = (unsigned short*)(ws + (32u << 20));      // 8 MB [B,H,T,D]
  unsigned short* Ob   = (unsigned short*)(ws + (40u << 20));      // 8 MB [B,T,E]
  unsigned short* Vtb  = xb;   // aliases xb: dead after GEMM1, Vtb written after

  cast_all<<<8192, 256, 0, stream>>>(x, Wq, Wk, Wv, Wp, xb, wqkv, wp);

  gemm_bt<0><<<dim3(32, 24), 256, 0, stream>>>(xb, wqkv, 4096, 3072, 1024,
                                               nullptr, nullptr, Qb, Kb, Vb);
  transpose_v<<<dim3(16, 64), 256, 0, stream>>>(Vb, Vtb);
  attn_kernel<<<dim3(8, 64), 512, 0, stream>>>(Qb, Kb, Vtb, Ob);
  gemm_bt<1><<<dim3(32, 8), 256, 0, stream>>>(Ob, wp, 4096, 1024, 1024,
                                              out, bp, nullptr, nullptr, nullptr);
}

// Round 8
// 100.369 us; speedup vs baseline: 1.2150x; 1.0354x over previous
//
#include <hip/hip_runtime.h>

// MHA: B=4 T=1024 E=1024 H=16 D=64, causal, f32 in/out, bf16 internal compute.
// cast -> GEMM1 (QKV plain [B,H,T,D]) -> transpose_v -> flash attn -> GEMM2 (+bias)
// R8: attn staging = T14 async reg-stage split (issue loads for t+1 before compute of t;
//     ds_write after barrier). Plain barrier-ordered ds ops only. + setprio + defer-max.

#define T_SZ 1024
#define E_SZ 1024
#define H_SZ 16
#define D_SZ 64

typedef __attribute__((ext_vector_type(8))) short bf16x8;
typedef __attribute__((ext_vector_type(4))) short bf16x4;
typedef __attribute__((ext_vector_type(4))) float f32x4;

static __device__ __forceinline__ unsigned short f2b(float f) {
  unsigned int u = __builtin_bit_cast(unsigned int, f);
  u += 0x7fffu + ((u >> 16) & 1u);   // RNE
  return (unsigned short)(u >> 16);
}

static __device__ __forceinline__ unsigned int cvt_pk(float lo, float hi) {
  unsigned int r;
  asm("v_cvt_pk_bf16_f32 %0, %1, %2" : "=v"(r) : "v"(lo), "v"(hi));
  return r;
}

static __device__ __forceinline__ void load_lds16(const void* g, void* l) {
  __builtin_amdgcn_global_load_lds(
      (const __attribute__((address_space(1))) void*)g,
      (__attribute__((address_space(3))) void*)l, 16, 0, 0);
}

// ---------------- fused cast f32 -> bf16 ----------------
__global__ void cast_all(const float* __restrict__ x, const float* __restrict__ wq,
                         const float* __restrict__ wk, const float* __restrict__ wv,
                         const float* __restrict__ wp,
                         unsigned short* __restrict__ xb,
                         unsigned short* __restrict__ wqkvb,
                         unsigned short* __restrict__ wpb) {
  int b = blockIdx.x;
  const float4* src;
  ushort4* dst;
  int i;
  if (b < 4096) {
    src = (const float4*)x; dst = (ushort4*)xb; i = b * 256 + threadIdx.x;
  } else {
    int a = (b - 4096) >> 10;
    i = ((b - 4096) & 1023) * 256 + threadIdx.x;
    src = (const float4*)(a == 0 ? wq : a == 1 ? wk : a == 2 ? wv : wp);
    dst = (ushort4*)(a == 3 ? wpb : wqkvb + (size_t)a * 1048576);
  }
  float4 v = src[i];
  ushort4 o;
  o.x = f2b(v.x); o.y = f2b(v.y); o.z = f2b(v.z); o.w = f2b(v.w);
  dst[i] = o;
}

// ---------------- GEMM C[M,N] = A[M,K] * B[N,K]^T ----------------
// 128x128 tile, 4 waves, BK=32, double-buffered LDS with prefetch.
template <int EPI>
__global__ void gemm_bt(const unsigned short* __restrict__ A,
                        const unsigned short* __restrict__ Bm,
                        int M, int N, int K,
                        float* __restrict__ outF, const float* __restrict__ bias,
                        unsigned short* __restrict__ Qb,
                        unsigned short* __restrict__ Kb,
                        unsigned short* __restrict__ Vb) {
  __shared__ __align__(16) char lds[32768];   // 2 x (As 8K | Bs 8K)
  const int tid = threadIdx.x;
  const int wid = tid >> 6;
  const int lane = tid & 63;
  const int llo = lane & 15, lhi = lane >> 4;
  const int row0 = blockIdx.x * 128, col0 = blockIdx.y * 128;
  const int wr = (wid >> 1) * 64, wc = (wid & 1) * 64;

  f32x4 acc[4][4];
#pragma unroll
  for (int m = 0; m < 4; ++m)
#pragma unroll
    for (int n = 0; n < 4; ++n) {
      f32x4 z = {0.f, 0.f, 0.f, 0.f};
      acc[m][n] = z;
    }

  auto stage = [&](int kt, char* base) {
#pragma unroll
    for (int c = 0; c < 2; ++c) {
      int off = c * 4096 + tid * 16;
      int r = off >> 6, cb = off & 63;
      load_lds16((const char*)A + ((size_t)(row0 + r) * K + kt) * 2 + cb,
                 base + c * 4096 + wid * 1024);
      load_lds16((const char*)Bm + ((size_t)(col0 + r) * K + kt) * 2 + cb,
                 base + 8192 + c * 4096 + wid * 1024);
    }
  };

  stage(0, lds);
  __syncthreads();
  int buf = 0;

  for (int kt = 0; kt < K; kt += 32) {
    char* cur = lds + buf * 16384;
    if (kt + 32 < K) stage(kt + 32, lds + (buf ^ 1) * 16384);

    bf16x8 af[4], bfr[4];
#pragma unroll
    for (int m = 0; m < 4; ++m)
      af[m] = *reinterpret_cast<const bf16x8*>(cur + (wr + m * 16 + llo) * 64 + lhi * 16);
#pragma unroll
    for (int n = 0; n < 4; ++n)
      bfr[n] = *reinterpret_cast<const bf16x8*>(cur + 8192 + (wc + n * 16 + llo) * 64 + lhi * 16);
#pragma unroll
    for (int m = 0; m < 4; ++m)
#pragma unroll
      for (int n = 0; n < 4; ++n)
        acc[m][n] = __builtin_amdgcn_mfma_f32_16x16x32_bf16(af[m], bfr[n], acc[m][n], 0, 0, 0);
    __syncthreads();
    buf ^= 1;
  }

#pragma unroll
  for (int m = 0; m < 4; ++m)
#pragma unroll
    for (int n = 0; n < 4; ++n)
#pragma unroll
      for (int r = 0; r < 4; ++r) {
        int grow = row0 + wr + m * 16 + lhi * 4 + r;
        int gcol = col0 + wc + n * 16 + llo;
        float v = acc[m][n][r];
        if (EPI == 0) {
          int b = grow >> 10, t = grow & 1023;
          int which = gcol >> 10, hd = gcol & 1023;
          int h = hd >> 6, d = hd & 63;
          unsigned short* dst = (which == 0) ? Qb : (which == 1) ? Kb : Vb;
          dst[(((size_t)(b * H_SZ + h)) * T_SZ + t) * D_SZ + d] = f2b(v);
        } else {
          outF[(size_t)grow * N + gcol] = v + bias[gcol];
        }
      }
}

// ---------------- V transpose: [B,H,T,D] -> [B,H,D,T], LDS-tiled ----------------
__global__ void transpose_v(const unsigned short* __restrict__ Vb,
                            unsigned short* __restrict__ Vtb) {
  __shared__ unsigned short tile[64 * 71 + 8];
  const int tid = threadIdx.x;
  const int bh = blockIdx.y;
  const int t0 = blockIdx.x * 64;
  const size_t base = (size_t)bh * (T_SZ * D_SZ);
#pragma unroll
  for (int u = 0; u < 2; ++u) {
    int cid = u * 256 + tid;
    int r = cid >> 3, ck = cid & 7;
    bf16x8 v = *reinterpret_cast<const bf16x8*>(Vb + base + (size_t)(t0 + r) * D_SZ + ck * 8);
#pragma unroll
    for (int j = 0; j < 8; ++j)
      tile[(ck * 8 + j) * 71 + r] = (unsigned short)v[j];
  }
  __syncthreads();
#pragma unroll
  for (int u = 0; u < 2; ++u) {
    int cid = u * 256 + tid;
    int d = cid >> 3, tc = cid & 7;
    bf16x8 o;
#pragma unroll
    for (int j = 0; j < 8; ++j)
      o[j] = (short)tile[d * 71 + tc * 8 + j];
    *reinterpret_cast<bf16x8*>(Vtb + base + (size_t)d * T_SZ + t0 + tc * 8) = o;
  }
}

// ---------------- flash attention, causal, S^T layout, QBLK=128, 8 waves ----------------
// grid (8, 64) XCD-swizzled -> (blkx, bh); 512 thr = 8 waves x 16 q-rows, all parallel.
// R8 staging (T14): regs hold tile t (loaded last iter); per iter:
//   barrier -> ds_write tile t (swizzled) -> issue coalesced global loads for t+1
//   -> barrier -> compute tile t.  All LDS writes are plain ds ops ordered by barriers.
__global__ void attn_kernel(const unsigned short* __restrict__ Q,
                            const unsigned short* __restrict__ K,
                            const unsigned short* __restrict__ Vt,
                            unsigned short* __restrict__ O) {
  __shared__ __align__(16) char smem[32768];  // K 8K | V 8K | Ps 8x2K
  const int tid = threadIdx.x, wid = tid >> 6, lane = tid & 63;
  const int llo = lane & 15, lhi = lane >> 4;
  const int fid = blockIdx.y * 8 + blockIdx.x;
  const int wi = (fid & 7) * 64 + (fid >> 3);   // 8 bh per XCD -> K/V L2-resident
  const int blkx = wi & 7;
  const int bh = wi >> 3;
  const size_t bhbase = (size_t)bh * (T_SZ * D_SZ);
  char* Ks = smem;
  char* Vs = smem + 8192;
  char* Ps = smem + 16384 + wid * 2048;

  const int qrow = blkx * 128 + wid * 16 + llo;
  const int myqt = 2 * blkx + (wid >> 2);   // wave's last active tile (uniform)
  const int last = 2 * blkx + 1;
  bf16x8 bq[2];
  {
    const unsigned short* qp = Q + bhbase + (size_t)qrow * D_SZ + lhi * 8;
    bq[0] = *reinterpret_cast<const bf16x8*>(qp);
    bq[1] = *reinterpret_cast<const bf16x8*>(qp + 32);
  }

  // staging geometry: thread covers 16B of each 8KB tile
  const int soff = tid * 16;
  const int srow = soff >> 7;          // K: key row / V: d row  (0..63)
  const int sinb = soff & 127;         // byte within 128B row
  const int slds = srow * 128 + (sinb ^ ((srow & 7) << 4));   // swizzled LDS byte

  bf16x8 kreg, vreg;
  kreg = *reinterpret_cast<const bf16x8*>(K + bhbase + (size_t)srow * D_SZ + (sinb >> 1));
  vreg = *reinterpret_cast<const bf16x8*>(Vt + bhbase + (size_t)srow * T_SZ + (sinb >> 1));

  f32x4 oacc[4];
#pragma unroll
  for (int dc = 0; dc < 4; ++dc) {
    f32x4 z = {0.f, 0.f, 0.f, 0.f};
    oacc[dc] = z;
  }
  float mrun = -1e30f, lrun = 0.f;
  const float scale = 0.125f;

  for (int it = 0; it <= last; ++it) {
    __syncthreads();   // previous compute done: LDS writable
    *reinterpret_cast<bf16x8*>(Ks + slds) = kreg;
    *reinterpret_cast<bf16x8*>(Vs + slds) = vreg;
    if (it < last) {   // issue next tile's loads; latency hides under compute
      const int kv = (it + 1) * 64;
      kreg = *reinterpret_cast<const bf16x8*>(
          K + bhbase + (size_t)(kv + srow) * D_SZ + (sinb >> 1));
      vreg = *reinterpret_cast<const bf16x8*>(
          Vt + bhbase + (size_t)srow * T_SZ + kv + (sinb >> 1));
    }
    __syncthreads();   // tile it visible to all waves

    const int kv = it * 64;
    if (it <= myqt) {   // wave-uniform causal skip
      // S^T = K Q^T : A = K rows (keys), B = Q^T
      f32x4 sacc[4];
#pragma unroll
      for (int c = 0; c < 4; ++c) { f32x4 z = {0.f, 0.f, 0.f, 0.f}; sacc[c] = z; }
      __builtin_amdgcn_s_setprio(1);
#pragma unroll
      for (int seg = 0; seg < 2; ++seg)
#pragma unroll
        for (int c = 0; c < 4; ++c) {
          int key = c * 16 + llo;
          bf16x8 ak = *reinterpret_cast<const bf16x8*>(
              Ks + key * 128 + ((seg * 64 + lhi * 16) ^ ((key & 7) << 4)));
          sacc[c] = __builtin_amdgcn_mfma_f32_16x16x32_bf16(ak, bq[seg], sacc[c], 0, 0, 0);
        }
      __builtin_amdgcn_s_setprio(0);

      // softmax: lane holds 16 S^T values of its q-row (keys c*16 + lhi*4 + r)
      const bool diag = (it == myqt);
      float p[4][4];
      float pm = -1e30f;
#pragma unroll
      for (int c = 0; c < 4; ++c)
#pragma unroll
        for (int r = 0; r < 4; ++r) {
          float s = sacc[c][r] * scale;
          if (diag && (kv + c * 16 + lhi * 4 + r > qrow)) s = -1e30f;
          p[c][r] = s;
          pm = fmaxf(pm, s);
        }
      pm = fmaxf(pm, __shfl_xor(pm, 16, 64));
      pm = fmaxf(pm, __shfl_xor(pm, 32, 64));
      // T13 defer-max: skip rescale while tile max stays within e^8 of running max
      if (!__all(pm - mrun <= 8.0f)) {
        float mnew = fmaxf(mrun, pm);
        float alpha = __expf(mrun - mnew);
        mrun = mnew;
        lrun *= alpha;
#pragma unroll
        for (int dc = 0; dc < 4; ++dc)
#pragma unroll
          for (int r = 0; r < 4; ++r) oacc[dc][r] *= alpha;
      }

      float ps = 0.f;
#pragma unroll
      for (int c = 0; c < 4; ++c) {
#pragma unroll
        for (int r = 0; r < 4; ++r) {
          p[c][r] = __expf(p[c][r] - mrun);
          ps += p[c][r];
        }
        unsigned int w0 = cvt_pk(p[c][0], p[c][1]);
        unsigned int w1 = cvt_pk(p[c][2], p[c][3]);
        unsigned long long packed = ((unsigned long long)w1 << 32) | w0;
        *reinterpret_cast<bf16x4*>(
            Ps + llo * 128 + ((c * 32 + lhi * 8) ^ ((llo & 7) << 4))) =
            __builtin_bit_cast(bf16x4, packed);
      }
      // Hard fence: Ps ds_writes retired before PV ds_reads (rule-18 pattern).
      asm volatile("s_waitcnt lgkmcnt(0)" ::: "memory");
      __builtin_amdgcn_sched_barrier(0);

      ps += __shfl_xor(ps, 16, 64);
      ps += __shfl_xor(ps, 32, 64);
      lrun += ps;

      // O^T += V^T P^T : A = V^T rows (d), B = P^T (from per-wave LDS)
      __builtin_amdgcn_s_setprio(1);
#pragma unroll
      for (int seg = 0; seg < 2; ++seg) {
        bf16x8 bp = *reinterpret_cast<const bf16x8*>(
            Ps + llo * 128 + ((seg * 64 + lhi * 16) ^ ((llo & 7) << 4)));
#pragma unroll
        for (int dc = 0; dc < 4; ++dc) {
          int d = dc * 16 + llo;
          bf16x8 av = *reinterpret_cast<const bf16x8*>(
              Vs + d * 128 + ((seg * 64 + lhi * 16) ^ ((d & 7) << 4)));
          oacc[dc] = __builtin_amdgcn_mfma_f32_16x16x32_bf16(av, bp, oacc[dc], 0, 0, 0);
        }
      }
      __builtin_amdgcn_s_setprio(0);
    }
  }

  // O^T -> O[b][t=q][h*64+d], d = dc*16 + lhi*4 + r
  const int b = bh >> 4, h = bh & 15;
  float inv = 1.f / lrun;
#pragma unroll
  for (int dc = 0; dc < 4; ++dc) {
    unsigned int w0 = cvt_pk(oacc[dc][0] * inv, oacc[dc][1] * inv);
    unsigned int w1 = cvt_pk(oacc[dc][2] * inv, oacc[dc][3] * inv);
    unsigned int* op = reinterpret_cast<unsigned int*>(
        O + ((size_t)b * T_SZ + qrow) * E_SZ + h * D_SZ + dc * 16 + lhi * 4);
    op[0] = w0;
    op[1] = w1;
  }
}

// ---------------- launch ----------------
extern "C" void kernel_launch(void* const* d_in, const int* in_sizes, int n_in,
                              void* d_out, int out_size, void* d_ws, size_t ws_size,
                              hipStream_t stream) {
  const float* x  = (const float*)d_in[0];
  const float* Wq = (const float*)d_in[1];
  const float* Wk = (const float*)d_in[2];
  const float* Wv = (const float*)d_in[3];
  const float* Wp = (const float*)d_in[4];
  const float* bp = (const float*)d_in[5];
  float* out = (float*)d_out;

  char* ws = (char*)d_ws;
  unsigned short* xb   = (unsigned short*)(ws);                    // 8 MB [4096,1024]
  unsigned short* wqkv = (unsigned short*)(ws + (8u << 20));       // 6 MB [3072,1024]
  unsigned short* wp   = (unsigned short*)(ws + (14u << 20));      // 2 MB [1024,1024]
  unsigned short* Qb   = (unsigned short*)(ws + (16u << 20));      // 8 MB [B,H,T,D]
  unsigned short* Kb   = (unsigned short*)(ws + (24u << 20));      // 8 MB [B,H,T,D]
  unsigned short* Vb   = (unsigned short*)(ws + (32u << 20));      // 8 MB [B,H,T,D]
  unsigned short* Ob   = (unsigned short*)(ws + (40u << 20));      // 8 MB [B,T,E]
  unsigned short* Vtb  = xb;   // aliases xb: dead after GEMM1, Vtb written after

  cast_all<<<8192, 256, 0, stream>>>(x, Wq, Wk, Wv, Wp, xb, wqkv, wp);

  gemm_bt<0><<<dim3(32, 24), 256, 0, stream>>>(xb, wqkv, 4096, 3072, 1024,
                                               nullptr, nullptr, Qb, Kb, Vb);
  transpose_v<<<dim3(16, 64), 256, 0, stream>>>(Vb, Vtb);
  attn_kernel<<<dim3(8, 64), 512, 0, stream>>>(Qb, Kb, Vtb, Ob);
  gemm_bt<1><<<dim3(32, 8), 256, 0, stream>>>(Ob, wp, 4096, 1024, 1024,
                                              out, bp, nullptr, nullptr, nullptr);
}

// Round 9
// 96.500 us; speedup vs baseline: 1.2637x; 1.0401x over previous
//
#include <hip/hip_runtime.h>

// MHA: B=4 T=1024 E=1024 H=16 D=64, causal, f32 in/out, bf16 internal compute.
// cast -> GEMM1 (QKV plain [B,H,T,D]) -> transpose_v -> flash attn -> GEMM2 (+bias)
// R9: GEMM BK 32->64 (2x MFMA per barrier drain, half the K-steps) + bank-spread
//     XOR swizzle on the 128B LDS rows (both-sides: pre-swizzled gload_lds source
//     + swizzled ds_read). Same R5-proven dbuf drain protocol. Attn unchanged.

#define T_SZ 1024
#define E_SZ 1024
#define H_SZ 16
#define D_SZ 64

typedef __attribute__((ext_vector_type(8))) short bf16x8;
typedef __attribute__((ext_vector_type(4))) short bf16x4;
typedef __attribute__((ext_vector_type(4))) float f32x4;

static __device__ __forceinline__ unsigned short f2b(float f) {
  unsigned int u = __builtin_bit_cast(unsigned int, f);
  u += 0x7fffu + ((u >> 16) & 1u);   // RNE
  return (unsigned short)(u >> 16);
}

static __device__ __forceinline__ unsigned int cvt_pk(float lo, float hi) {
  unsigned int r;
  asm("v_cvt_pk_bf16_f32 %0, %1, %2" : "=v"(r) : "v"(lo), "v"(hi));
  return r;
}

static __device__ __forceinline__ void load_lds16(const void* g, void* l) {
  __builtin_amdgcn_global_load_lds(
      (const __attribute__((address_space(1))) void*)g,
      (__attribute__((address_space(3))) void*)l, 16, 0, 0);
}

// ---------------- fused cast f32 -> bf16 ----------------
__global__ void cast_all(const float* __restrict__ x, const float* __restrict__ wq,
                         const float* __restrict__ wk, const float* __restrict__ wv,
                         const float* __restrict__ wp,
                         unsigned short* __restrict__ xb,
                         unsigned short* __restrict__ wqkvb,
                         unsigned short* __restrict__ wpb) {
  int b = blockIdx.x;
  const float4* src;
  ushort4* dst;
  int i;
  if (b < 4096) {
    src = (const float4*)x; dst = (ushort4*)xb; i = b * 256 + threadIdx.x;
  } else {
    int a = (b - 4096) >> 10;
    i = ((b - 4096) & 1023) * 256 + threadIdx.x;
    src = (const float4*)(a == 0 ? wq : a == 1 ? wk : a == 2 ? wv : wp);
    dst = (ushort4*)(a == 3 ? wpb : wqkvb + (size_t)a * 1048576);
  }
  float4 v = src[i];
  ushort4 o;
  o.x = f2b(v.x); o.y = f2b(v.y); o.z = f2b(v.z); o.w = f2b(v.w);
  dst[i] = o;
}

// ---------------- GEMM C[M,N] = A[M,K] * B[N,K]^T ----------------
// 128x128 tile, 4 waves, BK=64, dbuf (64KB LDS), drain protocol (R5-proven).
// LDS rows = 64 bf16 = 128B, XOR-swizzled: byte ^= ((row>>2)&3)<<5 (both sides).
template <int EPI>
__global__ void gemm_bt(const unsigned short* __restrict__ A,
                        const unsigned short* __restrict__ Bm,
                        int M, int N, int K,
                        float* __restrict__ outF, const float* __restrict__ bias,
                        unsigned short* __restrict__ Qb,
                        unsigned short* __restrict__ Kb,
                        unsigned short* __restrict__ Vb) {
  __shared__ __align__(16) char lds[65536];   // 2 x (As 16K | Bs 16K)
  const int tid = threadIdx.x;
  const int wid = tid >> 6;
  const int lane = tid & 63;
  const int llo = lane & 15, lhi = lane >> 4;
  const int row0 = blockIdx.x * 128, col0 = blockIdx.y * 128;
  const int wr = (wid >> 1) * 64, wc = (wid & 1) * 64;
  const int swl = ((llo >> 2) & 3) << 5;   // frag-read swizzle: row=16a+llo -> lane const

  f32x4 acc[4][4];
#pragma unroll
  for (int m = 0; m < 4; ++m)
#pragma unroll
    for (int n = 0; n < 4; ++n) {
      f32x4 z = {0.f, 0.f, 0.f, 0.f};
      acc[m][n] = z;
    }

  auto stage = [&](int kt, char* base) {
#pragma unroll
    for (int c = 0; c < 4; ++c) {
      int off = c * 4096 + tid * 16;       // byte in 16KB tile
      int r = off >> 7, cb = off & 127;    // row, byte-in-row (BK=64 bf16 = 128B)
      int sb = cb ^ (((r >> 2) & 3) << 5); // inverse-swizzled SOURCE chunk
      load_lds16((const char*)A + ((size_t)(row0 + r) * K + kt) * 2 + sb,
                 base + c * 4096 + wid * 1024);
      load_lds16((const char*)Bm + ((size_t)(col0 + r) * K + kt) * 2 + sb,
                 base + 16384 + c * 4096 + wid * 1024);
    }
  };

  stage(0, lds);
  __syncthreads();
  int buf = 0;

  for (int kt = 0; kt < K; kt += 64) {
    char* cur = lds + buf * 32768;
    if (kt + 64 < K) stage(kt + 64, lds + (buf ^ 1) * 32768);

    bf16x8 af[4][2], bfr[4][2];
#pragma unroll
    for (int m = 0; m < 4; ++m)
#pragma unroll
      for (int kk = 0; kk < 2; ++kk)
        af[m][kk] = *reinterpret_cast<const bf16x8*>(
            cur + (wr + m * 16 + llo) * 128 + ((kk * 64 + lhi * 16) ^ swl));
#pragma unroll
    for (int n = 0; n < 4; ++n)
#pragma unroll
      for (int kk = 0; kk < 2; ++kk)
        bfr[n][kk] = *reinterpret_cast<const bf16x8*>(
            cur + 16384 + (wc + n * 16 + llo) * 128 + ((kk * 64 + lhi * 16) ^ swl));
#pragma unroll
    for (int m = 0; m < 4; ++m)
#pragma unroll
      for (int n = 0; n < 4; ++n)
#pragma unroll
        for (int kk = 0; kk < 2; ++kk)
          acc[m][n] = __builtin_amdgcn_mfma_f32_16x16x32_bf16(af[m][kk], bfr[n][kk],
                                                              acc[m][n], 0, 0, 0);
    __syncthreads();   // drains vmcnt (next tile staged) + lgkmcnt
    buf ^= 1;
  }

#pragma unroll
  for (int m = 0; m < 4; ++m)
#pragma unroll
    for (int n = 0; n < 4; ++n)
#pragma unroll
      for (int r = 0; r < 4; ++r) {
        int grow = row0 + wr + m * 16 + lhi * 4 + r;
        int gcol = col0 + wc + n * 16 + llo;
        float v = acc[m][n][r];
        if (EPI == 0) {
          int b = grow >> 10, t = grow & 1023;
          int which = gcol >> 10, hd = gcol & 1023;
          int h = hd >> 6, d = hd & 63;
          unsigned short* dst = (which == 0) ? Qb : (which == 1) ? Kb : Vb;
          dst[(((size_t)(b * H_SZ + h)) * T_SZ + t) * D_SZ + d] = f2b(v);
        } else {
          outF[(size_t)grow * N + gcol] = v + bias[gcol];
        }
      }
}

// ---------------- V transpose: [B,H,T,D] -> [B,H,D,T], LDS-tiled ----------------
__global__ void transpose_v(const unsigned short* __restrict__ Vb,
                            unsigned short* __restrict__ Vtb) {
  __shared__ unsigned short tile[64 * 71 + 8];
  const int tid = threadIdx.x;
  const int bh = blockIdx.y;
  const int t0 = blockIdx.x * 64;
  const size_t base = (size_t)bh * (T_SZ * D_SZ);
#pragma unroll
  for (int u = 0; u < 2; ++u) {
    int cid = u * 256 + tid;
    int r = cid >> 3, ck = cid & 7;
    bf16x8 v = *reinterpret_cast<const bf16x8*>(Vb + base + (size_t)(t0 + r) * D_SZ + ck * 8);
#pragma unroll
    for (int j = 0; j < 8; ++j)
      tile[(ck * 8 + j) * 71 + r] = (unsigned short)v[j];
  }
  __syncthreads();
#pragma unroll
  for (int u = 0; u < 2; ++u) {
    int cid = u * 256 + tid;
    int d = cid >> 3, tc = cid & 7;
    bf16x8 o;
#pragma unroll
    for (int j = 0; j < 8; ++j)
      o[j] = (short)tile[d * 71 + tc * 8 + j];
    *reinterpret_cast<bf16x8*>(Vtb + base + (size_t)d * T_SZ + t0 + tc * 8) = o;
  }
}

// ---------------- flash attention, causal, S^T layout, QBLK=128, 8 waves ----------------
// (R8 structure frozen: T14 reg-stage split + setprio + defer-max)
__global__ void attn_kernel(const unsigned short* __restrict__ Q,
                            const unsigned short* __restrict__ K,
                            const unsigned short* __restrict__ Vt,
                            unsigned short* __restrict__ O) {
  __shared__ __align__(16) char smem[32768];  // K 8K | V 8K | Ps 8x2K
  const int tid = threadIdx.x, wid = tid >> 6, lane = tid & 63;
  const int llo = lane & 15, lhi = lane >> 4;
  const int fid = blockIdx.y * 8 + blockIdx.x;
  const int wi = (fid & 7) * 64 + (fid >> 3);   // 8 bh per XCD -> K/V L2-resident
  const int blkx = wi & 7;
  const int bh = wi >> 3;
  const size_t bhbase = (size_t)bh * (T_SZ * D_SZ);
  char* Ks = smem;
  char* Vs = smem + 8192;
  char* Ps = smem + 16384 + wid * 2048;

  const int qrow = blkx * 128 + wid * 16 + llo;
  const int myqt = 2 * blkx + (wid >> 2);   // wave's last active tile (uniform)
  const int last = 2 * blkx + 1;
  bf16x8 bq[2];
  {
    const unsigned short* qp = Q + bhbase + (size_t)qrow * D_SZ + lhi * 8;
    bq[0] = *reinterpret_cast<const bf16x8*>(qp);
    bq[1] = *reinterpret_cast<const bf16x8*>(qp + 32);
  }

  const int soff = tid * 16;
  const int srow = soff >> 7;
  const int sinb = soff & 127;
  const int slds = srow * 128 + (sinb ^ ((srow & 7) << 4));

  bf16x8 kreg, vreg;
  kreg = *reinterpret_cast<const bf16x8*>(K + bhbase + (size_t)srow * D_SZ + (sinb >> 1));
  vreg = *reinterpret_cast<const bf16x8*>(Vt + bhbase + (size_t)srow * T_SZ + (sinb >> 1));

  f32x4 oacc[4];
#pragma unroll
  for (int dc = 0; dc < 4; ++dc) {
    f32x4 z = {0.f, 0.f, 0.f, 0.f};
    oacc[dc] = z;
  }
  float mrun = -1e30f, lrun = 0.f;
  const float scale = 0.125f;

  for (int it = 0; it <= last; ++it) {
    __syncthreads();   // previous compute done: LDS writable
    *reinterpret_cast<bf16x8*>(Ks + slds) = kreg;
    *reinterpret_cast<bf16x8*>(Vs + slds) = vreg;
    if (it < last) {   // issue next tile's loads; latency hides under compute
      const int kv = (it + 1) * 64;
      kreg = *reinterpret_cast<const bf16x8*>(
          K + bhbase + (size_t)(kv + srow) * D_SZ + (sinb >> 1));
      vreg = *reinterpret_cast<const bf16x8*>(
          Vt + bhbase + (size_t)srow * T_SZ + kv + (sinb >> 1));
    }
    __syncthreads();   // tile it visible to all waves

    const int kv = it * 64;
    if (it <= myqt) {   // wave-uniform causal skip
      f32x4 sacc[4];
#pragma unroll
      for (int c = 0; c < 4; ++c) { f32x4 z = {0.f, 0.f, 0.f, 0.f}; sacc[c] = z; }
      __builtin_amdgcn_s_setprio(1);
#pragma unroll
      for (int seg = 0; seg < 2; ++seg)
#pragma unroll
        for (int c = 0; c < 4; ++c) {
          int key = c * 16 + llo;
          bf16x8 ak = *reinterpret_cast<const bf16x8*>(
              Ks + key * 128 + ((seg * 64 + lhi * 16) ^ ((key & 7) << 4)));
          sacc[c] = __builtin_amdgcn_mfma_f32_16x16x32_bf16(ak, bq[seg], sacc[c], 0, 0, 0);
        }
      __builtin_amdgcn_s_setprio(0);

      const bool diag = (it == myqt);
      float p[4][4];
      float pm = -1e30f;
#pragma unroll
      for (int c = 0; c < 4; ++c)
#pragma unroll
        for (int r = 0; r < 4; ++r) {
          float s = sacc[c][r] * scale;
          if (diag && (kv + c * 16 + lhi * 4 + r > qrow)) s = -1e30f;
          p[c][r] = s;
          pm = fmaxf(pm, s);
        }
      pm = fmaxf(pm, __shfl_xor(pm, 16, 64));
      pm = fmaxf(pm, __shfl_xor(pm, 32, 64));
      if (!__all(pm - mrun <= 8.0f)) {   // T13 defer-max
        float mnew = fmaxf(mrun, pm);
        float alpha = __expf(mrun - mnew);
        mrun = mnew;
        lrun *= alpha;
#pragma unroll
        for (int dc = 0; dc < 4; ++dc)
#pragma unroll
          for (int r = 0; r < 4; ++r) oacc[dc][r] *= alpha;
      }

      float ps = 0.f;
#pragma unroll
      for (int c = 0; c < 4; ++c) {
#pragma unroll
        for (int r = 0; r < 4; ++r) {
          p[c][r] = __expf(p[c][r] - mrun);
          ps += p[c][r];
        }
        unsigned int w0 = cvt_pk(p[c][0], p[c][1]);
        unsigned int w1 = cvt_pk(p[c][2], p[c][3]);
        unsigned long long packed = ((unsigned long long)w1 << 32) | w0;
        *reinterpret_cast<bf16x4*>(
            Ps + llo * 128 + ((c * 32 + lhi * 8) ^ ((llo & 7) << 4))) =
            __builtin_bit_cast(bf16x4, packed);
      }
      asm volatile("s_waitcnt lgkmcnt(0)" ::: "memory");
      __builtin_amdgcn_sched_barrier(0);

      ps += __shfl_xor(ps, 16, 64);
      ps += __shfl_xor(ps, 32, 64);
      lrun += ps;

      __builtin_amdgcn_s_setprio(1);
#pragma unroll
      for (int seg = 0; seg < 2; ++seg) {
        bf16x8 bp = *reinterpret_cast<const bf16x8*>(
            Ps + llo * 128 + ((seg * 64 + lhi * 16) ^ ((llo & 7) << 4)));
#pragma unroll
        for (int dc = 0; dc < 4; ++dc) {
          int d = dc * 16 + llo;
          bf16x8 av = *reinterpret_cast<const bf16x8*>(
              Vs + d * 128 + ((seg * 64 + lhi * 16) ^ ((d & 7) << 4)));
          oacc[dc] = __builtin_amdgcn_mfma_f32_16x16x32_bf16(av, bp, oacc[dc], 0, 0, 0);
        }
      }
      __builtin_amdgcn_s_setprio(0);
    }
  }

  const int b = bh >> 4, h = bh & 15;
  float inv = 1.f / lrun;
#pragma unroll
  for (int dc = 0; dc < 4; ++dc) {
    unsigned int w0 = cvt_pk(oacc[dc][0] * inv, oacc[dc][1] * inv);
    unsigned int w1 = cvt_pk(oacc[dc][2] * inv, oacc[dc][3] * inv);
    unsigned int* op = reinterpret_cast<unsigned int*>(
        O + ((size_t)b * T_SZ + qrow) * E_SZ + h * D_SZ + dc * 16 + lhi * 4);
    op[0] = w0;
    op[1] = w1;
  }
}

// ---------------- launch ----------------
extern "C" void kernel_launch(void* const* d_in, const int* in_sizes, int n_in,
                              void* d_out, int out_size, void* d_ws, size_t ws_size,
                              hipStream_t stream) {
  const float* x  = (const float*)d_in[0];
  const float* Wq = (const float*)d_in[1];
  const float* Wk = (const float*)d_in[2];
  const float* Wv = (const float*)d_in[3];
  const float* Wp = (const float*)d_in[4];
  const float* bp = (const float*)d_in[5];
  float* out = (float*)d_out;

  char* ws = (char*)d_ws;
  unsigned short* xb   = (unsigned short*)(ws);                    // 8 MB [4096,1024]
  unsigned short* wqkv = (unsigned short*)(ws + (8u << 20));       // 6 MB [3072,1024]
  unsigned short* wp   = (unsigned short*)(ws + (14u << 20));      // 2 MB [1024,1024]
  unsigned short* Qb   = (unsigned short*)(ws + (16u << 20));      // 8 MB [B,H,T,D]
  unsigned short* Kb   = (unsigned short*)(ws + (24u << 20));      // 8 MB [B,H,T,D]
  unsigned short* Vb   = (unsigned short*)(ws + (32u << 20));      // 8 MB [B,H,T,D]
  unsigned short* Ob   = (unsigned short*)(ws + (40u << 20));      // 8 MB [B,T,E]
  unsigned short* Vtb  = xb;   // aliases xb: dead after GEMM1, Vtb written after

  cast_all<<<8192, 256, 0, stream>>>(x, Wq, Wk, Wv, Wp, xb, wqkv, wp);

  gemm_bt<0><<<dim3(32, 24), 256, 0, stream>>>(xb, wqkv, 4096, 3072, 1024,
                                               nullptr, nullptr, Qb, Kb, Vb);
  transpose_v<<<dim3(16, 64), 256, 0, stream>>>(Vb, Vtb);
  attn_kernel<<<dim3(8, 64), 512, 0, stream>>>(Qb, Kb, Vtb, Ob);
  gemm_bt<1><<<dim3(32, 8), 256, 0, stream>>>(Ob, wp, 4096, 1024, 1024,
                                              out, bp, nullptr, nullptr, nullptr);
}